// Round 13
// baseline (305.270 us; speedup 1.0000x reference)
//
#include <hip/hip_runtime.h>
#include <math.h>

#define D 256
#define B 16
#define L 8
#define N 128
#define NBLK 256

static constexpr float LAMBDA_ASYNC = 0.08f;
static constexpr float LAMBDA_TAU   = 0.12f;

// ws layout (floats):
//   acct[4096]  @ 0     (pre-scaled vin for next layer, [d][b])
//   fired[128]  @ 4096
//   ctr[32u]    @ 4224  (barrier counters — memset to 0 each call)
//   slab[128][4096] @ 4272  (per-node tanh-input partials, 2 MB)
#define OFF_FIRED 4096
#define OFF_CTR   4224
#define OFF_SLAB  4272

// Lean grid barrier: release-arrive, RELAXED spin (+s_sleep), single acquire.
// R5's regression was ACQUIRE-per-poll (L2 invalidate storm); this does one
// wbl2/inv pair per block per barrier.
__device__ __forceinline__ void gridbar(unsigned* ctr, int slot) {
    __syncthreads();
    if (threadIdx.x == 0) {
        __hip_atomic_fetch_add(&ctr[slot], 1u, __ATOMIC_RELEASE,
                               __HIP_MEMORY_SCOPE_AGENT);
        while (__hip_atomic_load(&ctr[slot], __ATOMIC_RELAXED,
                                 __HIP_MEMORY_SCOPE_AGENT) < (unsigned)NBLK)
            __builtin_amdgcn_s_sleep(4);
        (void)__hip_atomic_load(&ctr[slot], __ATOMIC_ACQUIRE,
                                __HIP_MEMORY_SCOPE_AGENT);
    }
    __syncthreads();
}

// 256 blocks = (node n, e-half h), 512 thr = 8 waves. One block per CU.
// Per layer: [stage vin + firing + W-phase] bar [distributed reduce] bar.
__global__ __launch_bounds__(512, 2) void fused_kernel(
    const float* __restrict__ X,      // B*D
    const float* __restrict__ W,      // L*N*D*D
    const float* __restrict__ bias,   // L*N*D
    const float* __restrict__ S,      // L*N*D
    const float* __restrict__ rho,    // L*N
    const float* __restrict__ boost,  // L*N
    const int*  __restrict__ tb,
    float* __restrict__ ws,
    float* __restrict__ out)
{
    __shared__ float vin[D * 16];        // [d][b], 16 KB
    __shared__ float red[4 * 64 * 33];   // cross-wave partials, 33.8 KB
    __shared__ float part[512];          // reduce-phase partials, 2 KB
    __shared__ float sh[8];

    const int t    = threadIdx.x;
    const int w    = t >> 6;
    const int lane = t & 63;
    const int n    = blockIdx.x >> 1;
    const int h    = blockIdx.x & 1;
    const int e0   = h * 128;
    const int eR   = blockIdx.x;         // reduce-phase e owned by this block

    float*    acct  = ws;
    float*    fired = ws + OFF_FIRED;
    unsigned* ctr   = (unsigned*)(ws + OFF_CTR);
    float*    slab  = ws + OFF_SLAB;

    const float tbf = (float)tb[0];
    float cnt_prev = 1.0f;               // layer 0: has_input = true

    for (int l = 0; l < L; ++l) {
        // ---- stage vin into LDS as [d][b]
        if (l == 0) {
            if (t < 256) {
                #pragma unroll
                for (int k = 0; k < 2; ++k) {
                    const float4 xv = ((const float4*)X)[t * 2 + k];
                    const int idx = (t * 2 + k) * 4;   // = b*256 + d0
                    const int b   = idx >> 8;
                    const int d0  = idx & 255;
                    vin[(d0 + 0) * 16 + b] = xv.x;
                    vin[(d0 + 1) * 16 + b] = xv.y;
                    vin[(d0 + 2) * 16 + b] = xv.z;
                    vin[(d0 + 3) * 16 + b] = xv.w;
                }
            }
        } else {
            const float4* s4 = (const float4*)acct;
            ((float4*)vin)[t * 2 + 0] = s4[t * 2 + 0];
            ((float4*)vin)[t * 2 + 1] = s4[t * 2 + 1];
        }
        __syncthreads();

        // ---- firing preamble: part = colsum[d=t] * S[n][t]  (t<256)
        float p = 0.0f;
        if (t < 256) {
            const float4 a0 = *(const float4*)&vin[t * 16 + 0];
            const float4 a1 = *(const float4*)&vin[t * 16 + 4];
            const float4 a2 = *(const float4*)&vin[t * 16 + 8];
            const float4 a3 = *(const float4*)&vin[t * 16 + 12];
            const float cs = a0.x + a0.y + a0.z + a0.w + a1.x + a1.y + a1.z + a1.w
                           + a2.x + a2.y + a2.z + a2.w + a3.x + a3.y + a3.z + a3.w;
            p = cs * S[(size_t)(l * N + n) * D + t];
        }
        #pragma unroll
        for (int o = 32; o > 0; o >>= 1) p += __shfl_down(p, o);
        if (lane == 0) sh[w] = p;
        __syncthreads();

        {
            const bool has_input = (l == 0) ? true : (cnt_prev > 0.0f);
            const float sdot = (sh[0] + sh[1] + sh[2] + sh[3]) * (1.0f / 16.0f);
            const float tau  = 0.5f * expf(LAMBDA_TAU * ((float)(l + 1) - tbf));
            const bool fired_n =
                (rho[l * N + n] + sdot + boost[l * N + n] >= tau) && has_input;
            if (h == 0 && t == 0) fired[n] = fired_n ? 1.0f : 0.0f;

            if (fired_n) {   // block-uniform branch (internal syncthreads OK)
                const float* wp = W + (size_t)(l * N + n) * D * D + (e0 + lane * 2);
                const int dbase = w * 32;

                float accA[16], accB[16];
                #pragma unroll
                for (int b = 0; b < 16; ++b) { accA[b] = 0.0f; accB[b] = 0.0f; }

                #pragma unroll
                for (int j = 0; j < 32; j += 4) {
                    float2 wv[4];
                    #pragma unroll
                    for (int i = 0; i < 4; ++i)
                        wv[i] = *(const float2*)(wp + (size_t)(dbase + j + i) * 256);
                    #pragma unroll
                    for (int i = 0; i < 4; ++i) {
                        const float* vr = &vin[(dbase + j + i) * 16];
                        const float4 v0 = *(const float4*)(vr + 0);
                        const float4 v1 = *(const float4*)(vr + 4);
                        const float4 v2 = *(const float4*)(vr + 8);
                        const float4 v3 = *(const float4*)(vr + 12);
                        const float wx = wv[i].x, wy = wv[i].y;
                        accA[ 0] = fmaf(wx, v0.x, accA[ 0]); accB[ 0] = fmaf(wy, v0.x, accB[ 0]);
                        accA[ 1] = fmaf(wx, v0.y, accA[ 1]); accB[ 1] = fmaf(wy, v0.y, accB[ 1]);
                        accA[ 2] = fmaf(wx, v0.z, accA[ 2]); accB[ 2] = fmaf(wy, v0.z, accB[ 2]);
                        accA[ 3] = fmaf(wx, v0.w, accA[ 3]); accB[ 3] = fmaf(wy, v0.w, accB[ 3]);
                        accA[ 4] = fmaf(wx, v1.x, accA[ 4]); accB[ 4] = fmaf(wy, v1.x, accB[ 4]);
                        accA[ 5] = fmaf(wx, v1.y, accA[ 5]); accB[ 5] = fmaf(wy, v1.y, accB[ 5]);
                        accA[ 6] = fmaf(wx, v1.z, accA[ 6]); accB[ 6] = fmaf(wy, v1.z, accB[ 6]);
                        accA[ 7] = fmaf(wx, v1.w, accA[ 7]); accB[ 7] = fmaf(wy, v1.w, accB[ 7]);
                        accA[ 8] = fmaf(wx, v2.x, accA[ 8]); accB[ 8] = fmaf(wy, v2.x, accB[ 8]);
                        accA[ 9] = fmaf(wx, v2.y, accA[ 9]); accB[ 9] = fmaf(wy, v2.y, accB[ 9]);
                        accA[10] = fmaf(wx, v2.z, accA[10]); accB[10] = fmaf(wy, v2.z, accB[10]);
                        accA[11] = fmaf(wx, v2.w, accA[11]); accB[11] = fmaf(wy, v2.w, accB[11]);
                        accA[12] = fmaf(wx, v3.x, accA[12]); accB[12] = fmaf(wy, v3.x, accB[12]);
                        accA[13] = fmaf(wx, v3.y, accA[13]); accB[13] = fmaf(wy, v3.y, accB[13]);
                        accA[14] = fmaf(wx, v3.z, accA[14]); accB[14] = fmaf(wy, v3.z, accB[14]);
                        accA[15] = fmaf(wx, v3.w, accA[15]); accB[15] = fmaf(wy, v3.w, accB[15]);
                    }
                }

                // cross-wave reduce: waves 4-7 write slots 0-3, waves 0-3 add
                float* rr = &red[((w & 3) * 64 + lane) * 33];
                if (w >= 4) {
                    #pragma unroll
                    for (int b = 0; b < 16; ++b) { rr[b] = accA[b]; rr[16 + b] = accB[b]; }
                }
                __syncthreads();
                if (w < 4) {
                    #pragma unroll
                    for (int b = 0; b < 16; ++b) { rr[b] += accA[b]; rr[16 + b] += accB[b]; }
                }
                __syncthreads();

                // epilogue: thread -> 4 cells; raw sum (no bias/tanh) -> slab
                const int e_loc = t >> 2;
                const int b0    = (t & 3) * 4;
                const int lane2 = e_loc >> 1;
                const int sub   = e_loc & 1;
                const int o0    = sub * 16 + b0;
                float4 o4;
                o4.x = red[(0*64+lane2)*33 + o0+0] + red[(1*64+lane2)*33 + o0+0]
                     + red[(2*64+lane2)*33 + o0+0] + red[(3*64+lane2)*33 + o0+0];
                o4.y = red[(0*64+lane2)*33 + o0+1] + red[(1*64+lane2)*33 + o0+1]
                     + red[(2*64+lane2)*33 + o0+1] + red[(3*64+lane2)*33 + o0+1];
                o4.z = red[(0*64+lane2)*33 + o0+2] + red[(1*64+lane2)*33 + o0+2]
                     + red[(2*64+lane2)*33 + o0+2] + red[(3*64+lane2)*33 + o0+2];
                o4.w = red[(0*64+lane2)*33 + o0+3] + red[(1*64+lane2)*33 + o0+3]
                     + red[(2*64+lane2)*33 + o0+3] + red[(3*64+lane2)*33 + o0+3];
                *(float4*)(slab + (size_t)n * 4096 + (size_t)(e0 + e_loc) * 16 + b0) = o4;
            }
        }

        // ---- barrier 1: slab + fired visible everywhere
        gridbar(ctr, 2 * l);

        // ---- distributed reduce: this block owns e = eR (16 cells)
        {
            const int rb = t & 15;          // b
            const int rk = t >> 4;          // node-group (4 nodes each)
            const float* bcol = bias + (size_t)l * N * D + eR;
            float s = 0.0f;
            #pragma unroll
            for (int j = 0; j < 4; ++j) {
                const int n2 = rk * 4 + j;
                const float f = fired[n2];
                if (f > 0.0f)
                    s += tanhf(slab[(size_t)n2 * 4096 + (size_t)eR * 16 + rb]
                               + bcol[(size_t)n2 * D]);
            }
            part[t] = s;

            if (t < 64) {                    // wave 0: fired count
                float c = fired[t] + fired[t + 64];
                #pragma unroll
                for (int o = 32; o > 0; o >>= 1) c += __shfl_down(c, o);
                if (t == 0) sh[0] = c;
            }
            __syncthreads();

            const float cnt = sh[0];
            if (t < 16) {
                float tot = 0.0f;
                #pragma unroll
                for (int k = 0; k < 32; ++k) tot += part[k * 16 + t];
                if (l < L - 1) {
                    const float scale = expf(-LAMBDA_ASYNC) / fmaxf(cnt, 1.0f);
                    acct[eR * 16 + t] = tot * scale;
                } else {
                    out[t * 256 + eR] = tot / fmaxf(cnt, 1.0f);
                }
            }
            cnt_prev = cnt;
        }

        // ---- barrier 2: acct visible before next layer stages it
        if (l < L - 1) gridbar(ctr, 2 * l + 1);
    }
}

extern "C" void kernel_launch(void* const* d_in, const int* in_sizes, int n_in,
                              void* d_out, int out_size, void* d_ws, size_t ws_size,
                              hipStream_t stream)
{
    const float* X     = (const float*)d_in[0];
    const float* W     = (const float*)d_in[1];
    const float* bias  = (const float*)d_in[2];
    const float* S     = (const float*)d_in[3];
    const float* rho   = (const float*)d_in[4];
    const float* boost = (const float*)d_in[5];
    const int*   tb    = (const int*)d_in[6];
    float* out = (float*)d_out;
    float* ws  = (float*)d_ws;

    // zero the 32 barrier counters (128 B) every call — graph-capturable
    hipMemsetAsync((char*)d_ws + (size_t)OFF_CTR * sizeof(float), 0, 128, stream);

    fused_kernel<<<dim3(NBLK), dim3(512), 0, stream>>>(
        X, W, bias, S, rho, boost, tb, ws, out);
}

// Round 14
// 255.499 us; speedup vs baseline: 1.1948x; 1.1948x over previous
//
#include <hip/hip_runtime.h>
#include <math.h>

#define D 256
#define B 16
#define L 8
#define N 128

static constexpr float LAMBDA_ASYNC = 0.08f;
static constexpr float LAMBDA_TAU   = 0.12f;

// ws layout (floats) — single rotating buffers (stream strictly serial):
//   acct[4096]   @ 0      (pre-scaled vin for next layer, [d][b])
//   colsum[256]  @ 4096   (per-d column sums of CURRENT vin, l>=1)
//   meta[16]     @ 4352   (meta[0] = fired count of previous layer)
//   fired[128]   @ 4368
//   slab[128][4096] @ 4496  (raw per-node sums, [e][b]; 2 MB)
// No zeroing needed: consumed values rewritten each call; stale slab entries
// are masked by fired=0 (poison 0xAA = -3e-13f is finite).

#define OFF_COLSUM 4096
#define OFF_META   4352
#define OFF_FIRED  4368
#define OFF_SLAB   4496

// Grid: 256 blocks = (node n, e-half h). Block: 512 thr = 8 waves.
// Wave w owns d-rows [w*32, w*32+32); lane owns e-pair e0+lane*2+{0,1}.
// Hot loop per d-row: 1 global_load_dwordx2 of W (512 B/wave, coalesced)
// + 4 broadcast ds_read_b128 (vin row) + 32 FMAs. Raw sums -> slab.
// No atomics, no fences, no min-occupancy cap (R11 spill lesson).
__global__ __launch_bounds__(512) void layer_kernel(
    const float* __restrict__ Wl,         // N*D*D (this layer)
    const float* __restrict__ Sl,         // N*D
    const float* __restrict__ rhol,       // N
    const float* __restrict__ boostl,     // N
    const int*  __restrict__ tb,
    const float* __restrict__ vin_src,    // acct [d][b] pre-scaled (l>0)
    const float* __restrict__ X,          // B*D (l==0)
    const float* __restrict__ colsum,     // [256] (l>0)
    const float* __restrict__ meta_prev,  // fired count prev layer (null l==0)
    float* __restrict__ slab,             // [n][4096] raw sums
    float* __restrict__ fired_cur,        // N
    float depth, int is_first)
{
    __shared__ float vin[D * 16];        // [d][b], 16 KB
    __shared__ float red[4 * 64 * 33];   // cross-wave partials, 33.8 KB
    __shared__ float sh[8];

    const int t    = threadIdx.x;
    const int w    = t >> 6;
    const int lane = t & 63;
    const int n    = blockIdx.x >> 1;
    const int h    = blockIdx.x & 1;
    const int e0   = h * 128;

    float part = 0.0f;
    if (is_first) {
        // stage X transposed into LDS, then derive colsum from it
        if (t < 256) {
            #pragma unroll
            for (int k = 0; k < 2; ++k) {
                const float4 xv = ((const float4*)X)[t * 2 + k];
                const int idx = (t * 2 + k) * 4;   // = b*256 + d0
                const int b   = idx >> 8;
                const int d0  = idx & 255;
                vin[(d0 + 0) * 16 + b] = xv.x;
                vin[(d0 + 1) * 16 + b] = xv.y;
                vin[(d0 + 2) * 16 + b] = xv.z;
                vin[(d0 + 3) * 16 + b] = xv.w;
            }
        }
        __syncthreads();
        if (t < 256) {
            const float4 a0 = *(const float4*)&vin[t * 16 + 0];
            const float4 a1 = *(const float4*)&vin[t * 16 + 4];
            const float4 a2 = *(const float4*)&vin[t * 16 + 8];
            const float4 a3 = *(const float4*)&vin[t * 16 + 12];
            const float cs = a0.x + a0.y + a0.z + a0.w + a1.x + a1.y + a1.z + a1.w
                           + a2.x + a2.y + a2.z + a2.w + a3.x + a3.y + a3.z + a3.w;
            part = cs * Sl[n * D + t];
        }
    } else {
        // firing preamble from global colsum (1 KB) — BEFORE staging
        if (t < 256) part = colsum[t] * Sl[n * D + t];
    }
    #pragma unroll
    for (int o = 32; o > 0; o >>= 1) part += __shfl_down(part, o);
    if (lane == 0) sh[w] = part;
    __syncthreads();

    {
        const bool has_input = is_first ? true : (meta_prev[0] > 0.0f);
        const float sdot = (sh[0] + sh[1] + sh[2] + sh[3]) * (1.0f / 16.0f);
        const float tau  = 0.5f * expf(LAMBDA_TAU * (depth - (float)tb[0]));
        const bool fired = (rhol[n] + sdot + boostl[n] >= tau) && has_input;
        if (h == 0 && t == 0) fired_cur[n] = fired ? 1.0f : 0.0f;
        if (!fired) return;   // block-uniform: skip staging (l>0) + W stream
    }

    if (!is_first) {
        const float4* s4 = (const float4*)vin_src;
        ((float4*)vin)[t * 2 + 0] = s4[t * 2 + 0];
        ((float4*)vin)[t * 2 + 1] = s4[t * 2 + 1];
        __syncthreads();
    }

    // ---- main loop: 32 d-rows for this wave (R8's proven loop)
    const float* wp = Wl + (size_t)n * D * D + (e0 + lane * 2);
    const int dbase = w * 32;

    float accA[16], accB[16];
    #pragma unroll
    for (int b = 0; b < 16; ++b) { accA[b] = 0.0f; accB[b] = 0.0f; }

    #pragma unroll
    for (int j = 0; j < 32; j += 4) {
        float2 wv[4];
        #pragma unroll
        for (int i = 0; i < 4; ++i)
            wv[i] = *(const float2*)(wp + (size_t)(dbase + j + i) * 256);
        #pragma unroll
        for (int i = 0; i < 4; ++i) {
            const float* vr = &vin[(dbase + j + i) * 16];
            const float4 v0 = *(const float4*)(vr + 0);
            const float4 v1 = *(const float4*)(vr + 4);
            const float4 v2 = *(const float4*)(vr + 8);
            const float4 v3 = *(const float4*)(vr + 12);
            const float wx = wv[i].x, wy = wv[i].y;
            accA[ 0] = fmaf(wx, v0.x, accA[ 0]); accB[ 0] = fmaf(wy, v0.x, accB[ 0]);
            accA[ 1] = fmaf(wx, v0.y, accA[ 1]); accB[ 1] = fmaf(wy, v0.y, accB[ 1]);
            accA[ 2] = fmaf(wx, v0.z, accA[ 2]); accB[ 2] = fmaf(wy, v0.z, accB[ 2]);
            accA[ 3] = fmaf(wx, v0.w, accA[ 3]); accB[ 3] = fmaf(wy, v0.w, accB[ 3]);
            accA[ 4] = fmaf(wx, v1.x, accA[ 4]); accB[ 4] = fmaf(wy, v1.x, accB[ 4]);
            accA[ 5] = fmaf(wx, v1.y, accA[ 5]); accB[ 5] = fmaf(wy, v1.y, accB[ 5]);
            accA[ 6] = fmaf(wx, v1.z, accA[ 6]); accB[ 6] = fmaf(wy, v1.z, accB[ 6]);
            accA[ 7] = fmaf(wx, v1.w, accA[ 7]); accB[ 7] = fmaf(wy, v1.w, accB[ 7]);
            accA[ 8] = fmaf(wx, v2.x, accA[ 8]); accB[ 8] = fmaf(wy, v2.x, accB[ 8]);
            accA[ 9] = fmaf(wx, v2.y, accA[ 9]); accB[ 9] = fmaf(wy, v2.y, accB[ 9]);
            accA[10] = fmaf(wx, v2.z, accA[10]); accB[10] = fmaf(wy, v2.z, accB[10]);
            accA[11] = fmaf(wx, v2.w, accA[11]); accB[11] = fmaf(wy, v2.w, accB[11]);
            accA[12] = fmaf(wx, v3.x, accA[12]); accB[12] = fmaf(wy, v3.x, accB[12]);
            accA[13] = fmaf(wx, v3.y, accA[13]); accB[13] = fmaf(wy, v3.y, accB[13]);
            accA[14] = fmaf(wx, v3.z, accA[14]); accB[14] = fmaf(wy, v3.z, accB[14]);
            accA[15] = fmaf(wx, v3.w, accA[15]); accB[15] = fmaf(wy, v3.w, accB[15]);
        }
    }

    // ---- cross-wave reduce: waves 4-7 write slots 0-3, waves 0-3 add in
    {
        float* rr = &red[((w & 3) * 64 + lane) * 33];
        if (w >= 4) {
            #pragma unroll
            for (int b = 0; b < 16; ++b) { rr[b] = accA[b]; rr[16 + b] = accB[b]; }
        }
        __syncthreads();
        if (w < 4) {
            #pragma unroll
            for (int b = 0; b < 16; ++b) { rr[b] += accA[b]; rr[16 + b] += accB[b]; }
        }
        __syncthreads();
    }

    // ---- epilogue: thread -> 4 cells; RAW sum -> slab (bias/tanh in reduce)
    {
        const int e_loc = t >> 2;
        const int b0    = (t & 3) * 4;
        const int lane2 = e_loc >> 1;
        const int sub   = e_loc & 1;
        const int o0    = sub * 16 + b0;
        float4 o4;
        o4.x = red[(0*64+lane2)*33 + o0+0] + red[(1*64+lane2)*33 + o0+0]
             + red[(2*64+lane2)*33 + o0+0] + red[(3*64+lane2)*33 + o0+0];
        o4.y = red[(0*64+lane2)*33 + o0+1] + red[(1*64+lane2)*33 + o0+1]
             + red[(2*64+lane2)*33 + o0+1] + red[(3*64+lane2)*33 + o0+1];
        o4.z = red[(0*64+lane2)*33 + o0+2] + red[(1*64+lane2)*33 + o0+2]
             + red[(2*64+lane2)*33 + o0+2] + red[(3*64+lane2)*33 + o0+2];
        o4.w = red[(0*64+lane2)*33 + o0+3] + red[(1*64+lane2)*33 + o0+3]
             + red[(2*64+lane2)*33 + o0+3] + red[(3*64+lane2)*33 + o0+3];
        *(float4*)(slab + (size_t)n * 4096 + (size_t)(e0 + e_loc) * 16 + b0) = o4;
    }
}

// 64 blocks x 256 thr; thread = (cell, n-chunk of 32).  (R9's proven reduce)
// acct[c] = scale * sum_n fired[n]*tanh(slab[n][c] + bias[n][e]);
// colsum[d] = sum_b acct;  meta[0] = cnt.  IS_FINAL: out[b][e] = .../cnt.
template<bool IS_FINAL>
__global__ __launch_bounds__(256) void reduce_kernel(
    const float* __restrict__ slab, const float* __restrict__ biasl,
    const float* __restrict__ fired_l,
    float* __restrict__ acct, float* __restrict__ colsum,
    float* __restrict__ meta, float* __restrict__ out)
{
    __shared__ float part[256];
    __shared__ float shcnt;
    const int t    = threadIdx.x;
    const int cell = blockIdx.x * 64 + (t & 63);
    const int n0   = (t >> 6) * 32;
    const int e    = cell >> 4;

    float s = 0.0f;
    for (int k = 0; k < 32; ++k) {
        const int n = n0 + k;
        const float f = fired_l[n];
        if (f > 0.0f)                         // wave-uniform branch
            s += tanhf(slab[(size_t)n * 4096 + cell] + biasl[n * D + e]);
    }
    part[t] = s;

    if (t < 64) {                             // wave 0: fired count
        float c = fired_l[t] + fired_l[t + 64];
        #pragma unroll
        for (int o = 32; o > 0; o >>= 1) c += __shfl_down(c, o);
        if (t == 0) shcnt = c;
    }
    __syncthreads();

    if (t < 64) {
        const float cnt = shcnt;
        const int c = blockIdx.x * 64 + t;
        const float tot = part[t] + part[64 + t] + part[128 + t] + part[192 + t];
        if (IS_FINAL) {
            out[(c & 15) * 256 + (c >> 4)] = tot / fmaxf(cnt, 1.0f);
        } else {
            const float scale = expf(-LAMBDA_ASYNC) / fmaxf(cnt, 1.0f);
            const float v = tot * scale;
            acct[c] = v;
            float cs = v;                      // colsum over 16 b's per d
            cs += __shfl_down(cs, 8);
            cs += __shfl_down(cs, 4);
            cs += __shfl_down(cs, 2);
            cs += __shfl_down(cs, 1);
            if ((t & 15) == 0) colsum[c >> 4] = cs;
            if (blockIdx.x == 0 && t == 0) meta[0] = cnt;
        }
    }
}

extern "C" void kernel_launch(void* const* d_in, const int* in_sizes, int n_in,
                              void* d_out, int out_size, void* d_ws, size_t ws_size,
                              hipStream_t stream)
{
    const float* X     = (const float*)d_in[0];
    const float* W     = (const float*)d_in[1];
    const float* bias  = (const float*)d_in[2];
    const float* S     = (const float*)d_in[3];
    const float* rho   = (const float*)d_in[4];
    const float* boost = (const float*)d_in[5];
    const int*   tb    = (const int*)d_in[6];
    float* out = (float*)d_out;
    float* ws  = (float*)d_ws;

    float* acct   = ws;
    float* colsum = ws + OFF_COLSUM;
    float* meta   = ws + OFF_META;
    float* fired  = ws + OFF_FIRED;
    float* slab   = ws + OFF_SLAB;

    for (int l = 0; l < L; ++l) {
        layer_kernel<<<dim3(256), dim3(512), 0, stream>>>(
            W + (size_t)l * N * D * D,
            S + (size_t)l * N * D,
            rho + (size_t)l * N,
            boost + (size_t)l * N,
            tb,
            acct, X, colsum,
            (l == 0) ? (const float*)nullptr : meta,
            slab, fired,
            (float)(l + 1), (l == 0) ? 1 : 0);
        if (l < L - 1) {
            reduce_kernel<false><<<dim3(64), dim3(256), 0, stream>>>(
                slab, bias + (size_t)l * N * D, fired,
                acct, colsum, meta, out);
        } else {
            reduce_kernel<true><<<dim3(64), dim3(256), 0, stream>>>(
                slab, bias + (size_t)l * N * D, fired,
                acct, colsum, meta, out);
        }
    }
}

// Round 15
// 117.300 us; speedup vs baseline: 2.6025x; 2.1782x over previous
//
#include <hip/hip_runtime.h>
#include <math.h>

#define D 256
#define B 16
#define L 8
#define N 128

static constexpr float LAMBDA_ASYNC = 0.08f;
static constexpr float LAMBDA_TAU   = 0.12f;

// ws layout (floats) — single rotating buffers (stream strictly serial):
//   acct[4096]   @ 0      (pre-scaled vin for next layer, [d][b])
//   colsum[256]  @ 4096   (per-d column sums of CURRENT vin, l>=1)
//   meta[16]     @ 4352   (meta[0] = fired count of previous layer)
//   fired[128]   @ 4368
//   slab[128][4096] @ 4496  (per-node TANH'D tiles, [e][b]; 2 MB)
// Stale slab entries are masked by fired=0 via branchless multiply
// (poison 0xAA = -3e-13f is finite). NO conditional loads in the reduce:
// tanh-in-reduce + branch serialized cross-XCD misses (R11-R14, 255-305 us).

#define OFF_COLSUM 4096
#define OFF_META   4352
#define OFF_FIRED  4368
#define OFF_SLAB   4496

// Grid: 256 blocks = (node n, e-half h). Block: 512 thr = 8 waves.
// Wave w owns d-rows [w*32, w*32+32); lane owns e-pair e0+lane*2+{0,1}.
// Hot loop per d-row: 1 global_load_dwordx2 of W (512 B/wave, coalesced)
// + 4 broadcast ds_read_b128 (vin row) + 32 FMAs. tanh in epilogue -> slab.
__global__ __launch_bounds__(512) void layer_kernel(
    const float* __restrict__ Wl,         // N*D*D (this layer)
    const float* __restrict__ biasl,      // N*D
    const float* __restrict__ Sl,         // N*D
    const float* __restrict__ rhol,       // N
    const float* __restrict__ boostl,     // N
    const int*  __restrict__ tb,
    const float* __restrict__ vin_src,    // acct [d][b] pre-scaled (l>0)
    const float* __restrict__ X,          // B*D (l==0)
    const float* __restrict__ colsum,     // [256] (l>0)
    const float* __restrict__ meta_prev,  // fired count prev layer (null l==0)
    float* __restrict__ slab,             // [n][4096] tanh'd tiles
    float* __restrict__ fired_cur,        // N
    float depth, int is_first)
{
    __shared__ float vin[D * 16];        // [d][b], 16 KB
    __shared__ float red[4 * 64 * 33];   // cross-wave partials, 33.8 KB
    __shared__ float sh[8];

    const int t    = threadIdx.x;
    const int w    = t >> 6;
    const int lane = t & 63;
    const int n    = blockIdx.x >> 1;
    const int h    = blockIdx.x & 1;
    const int e0   = h * 128;

    float part = 0.0f;
    if (is_first) {
        // complete scalar transpose stage (R5-provenance, absmax 0.0)
        if (t < 256) {
            #pragma unroll
            for (int b = 0; b < 16; ++b) vin[t * 16 + b] = X[b * 256 + t];
        }
        __syncthreads();
        if (t < 256) {
            const float4 a0 = *(const float4*)&vin[t * 16 + 0];
            const float4 a1 = *(const float4*)&vin[t * 16 + 4];
            const float4 a2 = *(const float4*)&vin[t * 16 + 8];
            const float4 a3 = *(const float4*)&vin[t * 16 + 12];
            const float cs = a0.x + a0.y + a0.z + a0.w + a1.x + a1.y + a1.z + a1.w
                           + a2.x + a2.y + a2.z + a2.w + a3.x + a3.y + a3.z + a3.w;
            part = cs * Sl[n * D + t];
        }
    } else {
        // firing preamble from global colsum (1 KB) — BEFORE staging
        if (t < 256) part = colsum[t] * Sl[n * D + t];
    }
    #pragma unroll
    for (int o = 32; o > 0; o >>= 1) part += __shfl_down(part, o);
    if (lane == 0) sh[w] = part;
    __syncthreads();

    {
        const bool has_input = is_first ? true : (meta_prev[0] > 0.0f);
        const float sdot = (sh[0] + sh[1] + sh[2] + sh[3]) * (1.0f / 16.0f);
        const float tau  = 0.5f * expf(LAMBDA_TAU * (depth - (float)tb[0]));
        const bool fired = (rhol[n] + sdot + boostl[n] >= tau) && has_input;
        if (h == 0 && t == 0) fired_cur[n] = fired ? 1.0f : 0.0f;
        if (!fired) return;   // block-uniform: skip staging (l>0) + W stream
    }

    if (!is_first) {
        const float4* s4 = (const float4*)vin_src;
        ((float4*)vin)[t * 2 + 0] = s4[t * 2 + 0];
        ((float4*)vin)[t * 2 + 1] = s4[t * 2 + 1];
        __syncthreads();
    }

    // ---- main loop: 32 d-rows for this wave (R8/R9's proven loop)
    const float* wp = Wl + (size_t)n * D * D + (e0 + lane * 2);
    const int dbase = w * 32;

    float accA[16], accB[16];
    #pragma unroll
    for (int b = 0; b < 16; ++b) { accA[b] = 0.0f; accB[b] = 0.0f; }

    #pragma unroll
    for (int j = 0; j < 32; j += 4) {
        float2 wv[4];
        #pragma unroll
        for (int i = 0; i < 4; ++i)
            wv[i] = *(const float2*)(wp + (size_t)(dbase + j + i) * 256);
        #pragma unroll
        for (int i = 0; i < 4; ++i) {
            const float* vr = &vin[(dbase + j + i) * 16];
            const float4 v0 = *(const float4*)(vr + 0);
            const float4 v1 = *(const float4*)(vr + 4);
            const float4 v2 = *(const float4*)(vr + 8);
            const float4 v3 = *(const float4*)(vr + 12);
            const float wx = wv[i].x, wy = wv[i].y;
            accA[ 0] = fmaf(wx, v0.x, accA[ 0]); accB[ 0] = fmaf(wy, v0.x, accB[ 0]);
            accA[ 1] = fmaf(wx, v0.y, accA[ 1]); accB[ 1] = fmaf(wy, v0.y, accB[ 1]);
            accA[ 2] = fmaf(wx, v0.z, accA[ 2]); accB[ 2] = fmaf(wy, v0.z, accB[ 2]);
            accA[ 3] = fmaf(wx, v0.w, accA[ 3]); accB[ 3] = fmaf(wy, v0.w, accB[ 3]);
            accA[ 4] = fmaf(wx, v1.x, accA[ 4]); accB[ 4] = fmaf(wy, v1.x, accB[ 4]);
            accA[ 5] = fmaf(wx, v1.y, accA[ 5]); accB[ 5] = fmaf(wy, v1.y, accB[ 5]);
            accA[ 6] = fmaf(wx, v1.z, accA[ 6]); accB[ 6] = fmaf(wy, v1.z, accB[ 6]);
            accA[ 7] = fmaf(wx, v1.w, accA[ 7]); accB[ 7] = fmaf(wy, v1.w, accB[ 7]);
            accA[ 8] = fmaf(wx, v2.x, accA[ 8]); accB[ 8] = fmaf(wy, v2.x, accB[ 8]);
            accA[ 9] = fmaf(wx, v2.y, accA[ 9]); accB[ 9] = fmaf(wy, v2.y, accB[ 9]);
            accA[10] = fmaf(wx, v2.z, accA[10]); accB[10] = fmaf(wy, v2.z, accB[10]);
            accA[11] = fmaf(wx, v2.w, accA[11]); accB[11] = fmaf(wy, v2.w, accB[11]);
            accA[12] = fmaf(wx, v3.x, accA[12]); accB[12] = fmaf(wy, v3.x, accB[12]);
            accA[13] = fmaf(wx, v3.y, accA[13]); accB[13] = fmaf(wy, v3.y, accB[13]);
            accA[14] = fmaf(wx, v3.z, accA[14]); accB[14] = fmaf(wy, v3.z, accB[14]);
            accA[15] = fmaf(wx, v3.w, accA[15]); accB[15] = fmaf(wy, v3.w, accB[15]);
        }
    }

    // ---- cross-wave reduce: waves 4-7 write slots 0-3, waves 0-3 add in
    {
        float* rr = &red[((w & 3) * 64 + lane) * 33];
        if (w >= 4) {
            #pragma unroll
            for (int b = 0; b < 16; ++b) { rr[b] = accA[b]; rr[16 + b] = accB[b]; }
        }
        __syncthreads();
        if (w < 4) {
            #pragma unroll
            for (int b = 0; b < 16; ++b) { rr[b] += accA[b]; rr[16 + b] += accB[b]; }
        }
        __syncthreads();
    }

    // ---- epilogue: thread -> 4 cells; tanh(sum + bias) -> slab (vin pre-scaled)
    {
        const int e_loc = t >> 2;
        const int b0    = (t & 3) * 4;
        const int lane2 = e_loc >> 1;
        const int sub   = e_loc & 1;
        const int o0    = sub * 16 + b0;
        const float bv  = biasl[n * D + e0 + e_loc];
        float4 o4;
        o4.x = tanhf(red[(0*64+lane2)*33 + o0+0] + red[(1*64+lane2)*33 + o0+0]
                   + red[(2*64+lane2)*33 + o0+0] + red[(3*64+lane2)*33 + o0+0] + bv);
        o4.y = tanhf(red[(0*64+lane2)*33 + o0+1] + red[(1*64+lane2)*33 + o0+1]
                   + red[(2*64+lane2)*33 + o0+1] + red[(3*64+lane2)*33 + o0+1] + bv);
        o4.z = tanhf(red[(0*64+lane2)*33 + o0+2] + red[(1*64+lane2)*33 + o0+2]
                   + red[(2*64+lane2)*33 + o0+2] + red[(3*64+lane2)*33 + o0+2] + bv);
        o4.w = tanhf(red[(0*64+lane2)*33 + o0+3] + red[(1*64+lane2)*33 + o0+3]
                   + red[(2*64+lane2)*33 + o0+3] + red[(3*64+lane2)*33 + o0+3] + bv);
        *(float4*)(slab + (size_t)n * 4096 + (size_t)(e0 + e_loc) * 16 + b0) = o4;
    }
}

// 64 blocks x 256 thr; thread = (cell, n-chunk of 32). BRANCHLESS (R9/R10).
// acct[c] = scale * sum_n fired[n]*slab[n][c]; colsum[d] = sum_b acct;
// meta[0] = cnt.  IS_FINAL: out[b][e] = sum / max(cnt,1).
template<bool IS_FINAL>
__global__ __launch_bounds__(256) void reduce_kernel(
    const float* __restrict__ slab, const float* __restrict__ fired_l,
    float* __restrict__ acct, float* __restrict__ colsum,
    float* __restrict__ meta, float* __restrict__ out)
{
    __shared__ float part[256];
    __shared__ float shcnt;
    const int t    = threadIdx.x;
    const int cell = blockIdx.x * 64 + (t & 63);
    const int n0   = (t >> 6) * 32;

    float s = 0.0f;
    #pragma unroll 8
    for (int k = 0; k < 32; ++k)
        s = fmaf(fired_l[n0 + k], slab[(size_t)(n0 + k) * 4096 + cell], s);
    part[t] = s;

    if (t < 64) {                             // wave 0: fired count
        float c = fired_l[t] + fired_l[t + 64];
        #pragma unroll
        for (int o = 32; o > 0; o >>= 1) c += __shfl_down(c, o);
        if (t == 0) shcnt = c;
    }
    __syncthreads();

    if (t < 64) {
        const float cnt = shcnt;
        const int c = blockIdx.x * 64 + t;
        const float tot = part[t] + part[64 + t] + part[128 + t] + part[192 + t];
        if (IS_FINAL) {
            out[(c & 15) * 256 + (c >> 4)] = tot / fmaxf(cnt, 1.0f);
        } else {
            const float scale = expf(-LAMBDA_ASYNC) / fmaxf(cnt, 1.0f);
            const float v = tot * scale;
            acct[c] = v;
            float cs = v;                      // colsum over 16 b's per d
            cs += __shfl_down(cs, 8);
            cs += __shfl_down(cs, 4);
            cs += __shfl_down(cs, 2);
            cs += __shfl_down(cs, 1);
            if ((t & 15) == 0) colsum[c >> 4] = cs;
            if (blockIdx.x == 0 && t == 0) meta[0] = cnt;
        }
    }
}

extern "C" void kernel_launch(void* const* d_in, const int* in_sizes, int n_in,
                              void* d_out, int out_size, void* d_ws, size_t ws_size,
                              hipStream_t stream)
{
    const float* X     = (const float*)d_in[0];
    const float* W     = (const float*)d_in[1];
    const float* bias  = (const float*)d_in[2];
    const float* S     = (const float*)d_in[3];
    const float* rho   = (const float*)d_in[4];
    const float* boost = (const float*)d_in[5];
    const int*   tb    = (const int*)d_in[6];
    float* out = (float*)d_out;
    float* ws  = (float*)d_ws;

    float* acct   = ws;
    float* colsum = ws + OFF_COLSUM;
    float* meta   = ws + OFF_META;
    float* fired  = ws + OFF_FIRED;
    float* slab   = ws + OFF_SLAB;

    for (int l = 0; l < L; ++l) {
        layer_kernel<<<dim3(256), dim3(512), 0, stream>>>(
            W + (size_t)l * N * D * D,
            bias + (size_t)l * N * D,
            S + (size_t)l * N * D,
            rho + (size_t)l * N,
            boost + (size_t)l * N,
            tb,
            acct, X, colsum,
            (l == 0) ? (const float*)nullptr : meta,
            slab, fired,
            (float)(l + 1), (l == 0) ? 1 : 0);
        if (l < L - 1) {
            reduce_kernel<false><<<dim3(64), dim3(256), 0, stream>>>(
                slab, fired, acct, colsum, meta, out);
        } else {
            reduce_kernel<true><<<dim3(64), dim3(256), 0, stream>>>(
                slab, fired, acct, colsum, meta, out);
        }
    }
}